// Round 1
// baseline (1343.228 us; speedup 1.0000x reference)
//
#include <hip/hip_runtime.h>
#include <stdint.h>

#define NN 50000      // nodes
#define NRELS 3       // relations
#define NE 800000     // edges per relation
#define DIN 300
#define DH 256
#define NCHUNK 196    // ceil(NN/256)

__device__ __forceinline__ float bf2f(unsigned short u){
    union { unsigned int i; float f; } v; v.i = ((unsigned int)u) << 16; return v.f;
}
__device__ __forceinline__ unsigned short f2bf(float f){
    union { float f; unsigned int i; } v; v.f = f;
    return (unsigned short)((v.i + 0x7FFFu + ((v.i >> 16) & 1u)) >> 16);
}

// ---------------- attention softmax (6 scalars) ----------------
__global__ void k_att(const float* __restrict__ a_att, const float* __restrict__ r_att,
                      float* __restrict__ att){
    if (threadIdx.x == 0){
        float m = fmaxf(a_att[0], fmaxf(a_att[1], a_att[2]));
        float e0 = expf(a_att[0]-m), e1 = expf(a_att[1]-m), e2 = expf(a_att[2]-m);
        float s = e0+e1+e2;
        att[0]=e0/s; att[1]=e1/s; att[2]=e2/s;
        m = fmaxf(r_att[0], fmaxf(r_att[1], r_att[2]));
        e0 = expf(r_att[0]-m); e1 = expf(r_att[1]-m); e2 = expf(r_att[2]-m);
        s = e0+e1+e2;
        att[3]=e0/s; att[4]=e1/s; att[5]=e2/s;
    }
}

// ---------------- CSR build: histogram ----------------
__global__ void k_hist(const int* __restrict__ src, const int* __restrict__ dst,
                       int* __restrict__ counts){
    int rel = blockIdx.y;
    int e = blockIdx.x*256 + threadIdx.x;
    if (e >= NE) return;
    int d = dst[(size_t)rel*NE + e];
    int s = src[(size_t)rel*NE + e];
    atomicAdd(&counts[rel*NN + d], 1);           // layer1 rows = dst
    atomicAdd(&counts[(NRELS+rel)*NN + s], 1);   // layer2 rows = src
}

// ---------------- CSR build: two-level exclusive scan ----------------
__global__ void k_scanA(const int* __restrict__ counts, int* __restrict__ partials){
    __shared__ int lds[256];
    int a = blockIdx.y;
    int idx = blockIdx.x*256 + threadIdx.x;
    int v = (idx < NN) ? counts[a*NN + idx] : 0;
    lds[threadIdx.x] = v; __syncthreads();
    for (int off = 128; off > 0; off >>= 1){
        if (threadIdx.x < off) lds[threadIdx.x] += lds[threadIdx.x + off];
        __syncthreads();
    }
    if (threadIdx.x == 0) partials[a*NCHUNK + blockIdx.x] = lds[0];
}

__global__ void k_scanB(int* __restrict__ partials){
    __shared__ int lds[256];
    for (int a = 0; a < 6; ++a){
        int v = (threadIdx.x < NCHUNK) ? partials[a*NCHUNK + threadIdx.x] : 0;
        lds[threadIdx.x] = v; __syncthreads();
        for (int off = 1; off < 256; off <<= 1){
            int t = (threadIdx.x >= off) ? lds[threadIdx.x - off] : 0;
            __syncthreads();
            lds[threadIdx.x] += t;
            __syncthreads();
        }
        int incl = lds[threadIdx.x];
        if (threadIdx.x < NCHUNK) partials[a*NCHUNK + threadIdx.x] = incl - v; // exclusive
        __syncthreads();
    }
}

__global__ void k_scanC(const int* __restrict__ counts, const int* __restrict__ partials,
                        int* __restrict__ row_start){
    __shared__ int lds[256];
    int a = blockIdx.y;
    int idx = blockIdx.x*256 + threadIdx.x;
    int v = (idx < NN) ? counts[a*NN + idx] : 0;
    lds[threadIdx.x] = v; __syncthreads();
    for (int off = 1; off < 256; off <<= 1){
        int t = (threadIdx.x >= off) ? lds[threadIdx.x - off] : 0;
        __syncthreads();
        lds[threadIdx.x] += t;
        __syncthreads();
    }
    int excl = lds[threadIdx.x] - v + partials[a*NCHUNK + blockIdx.x];
    if (idx < NN) row_start[a*(NN+1) + idx] = excl;
    if (idx == NN-1) row_start[a*(NN+1) + NN] = excl + v;
}

// ---------------- CSR build: scatter sorted (col, val) ----------------
__global__ void k_scatter(const int* __restrict__ src, const int* __restrict__ dst,
                          const float* __restrict__ vals_a, const float* __restrict__ vals_r,
                          const int* __restrict__ row_start, int* __restrict__ cursor,
                          int* __restrict__ colS, float* __restrict__ valS){
    int rel = blockIdx.y;
    int e = blockIdx.x*256 + threadIdx.x;
    if (e >= NE) return;
    int s = src[(size_t)rel*NE + e];
    int d = dst[(size_t)rel*NE + e];
    {   // layer1: row=dst, col=src, val=vals_a
        int a = rel;
        int p = atomicAdd(&cursor[a*NN + d], 1);
        int slot = row_start[a*(NN+1) + d] + p;
        colS[(size_t)a*NE + slot] = s;
        valS[(size_t)a*NE + slot] = vals_a[(size_t)rel*NE + e];
    }
    {   // layer2: row=src, col=dst, val=vals_r
        int a = NRELS + rel;
        int p = atomicAdd(&cursor[a*NN + s], 1);
        int slot = row_start[a*(NN+1) + s] + p;
        colS[(size_t)a*NE + slot] = d;
        valS[(size_t)a*NE + slot] = vals_r[(size_t)rel*NE + e];
    }
}

// ---------------- GEMM: out[m][n] = A[m][:]@W[:][n] + b[n], bf16 out ----------------
template<int K, int BK, bool ABF16>
__global__ __launch_bounds__(256) void k_gemm(const void* __restrict__ Av,
                                              const float* __restrict__ W,
                                              const float* __restrict__ bias,
                                              unsigned short* __restrict__ out, int M){
    constexpr int BM = 32;
    __shared__ float ldsW[BK*DH];
    __shared__ float ldsX[BM*BK];
    const int tid = threadIdx.x;
    const int row0 = blockIdx.x * BM;
    const int jc = tid & 63;       // column group: cols jc*4 .. jc*4+3
    const int rg = tid >> 6;       // row group: rows rg*8 .. rg*8+7
    const float* Af = (const float*)Av;
    const unsigned short* Ab = (const unsigned short*)Av;
    float acc[8][4] = {};
    for (int k0 = 0; k0 < K; k0 += BK){
        for (int idx = tid; idx < BK*DH; idx += 256)
            ldsW[idx] = W[(size_t)k0*DH + idx];
        for (int idx = tid; idx < BM*BK; idx += 256){
            int r = idx / BK, k = idx % BK;
            int row = row0 + r;
            float x = 0.f;
            if (row < M){
                if (ABF16) x = bf2f(Ab[(size_t)row*K + k0 + k]);
                else       x = Af[(size_t)row*K + k0 + k];
            }
            ldsX[idx] = x;
        }
        __syncthreads();
        for (int k = 0; k < BK; ++k){
            const float4 wv = *(const float4*)(&ldsW[k*DH + jc*4]);
            #pragma unroll
            for (int r = 0; r < 8; ++r){
                float xv = ldsX[(rg*8 + r)*BK + k];
                acc[r][0] += xv*wv.x; acc[r][1] += xv*wv.y;
                acc[r][2] += xv*wv.z; acc[r][3] += xv*wv.w;
            }
        }
        __syncthreads();
    }
    const float4 bv = *(const float4*)(&bias[jc*4]);
    #pragma unroll
    for (int r = 0; r < 8; ++r){
        int row = row0 + rg*8 + r;
        if (row < M){
            ushort4 o;
            o.x = f2bf(acc[r][0] + bv.x);
            o.y = f2bf(acc[r][1] + bv.y);
            o.z = f2bf(acc[r][2] + bv.z);
            o.w = f2bf(acc[r][3] + bv.w);
            *(ushort4*)(&out[(size_t)row*DH + jc*4]) = o;
        }
    }
}

// ---------------- SPMM layer1 (gather by dst, fused LeakyReLU) ----------------
__global__ __launch_bounds__(256) void k_spmm1(const unsigned short* __restrict__ feat,
                                               const int* __restrict__ row_start,
                                               const int* __restrict__ colS,
                                               const float* __restrict__ valS,
                                               const float* __restrict__ att,
                                               unsigned short* __restrict__ out){
    int row = __builtin_amdgcn_readfirstlane(blockIdx.x*4 + (threadIdx.x >> 6));
    int lane = threadIdx.x & 63;
    if (row >= NN) return;
    float a0=0.f, a1=0.f, a2=0.f, a3=0.f;
    #pragma unroll
    for (int i = 0; i < NRELS; ++i){
        const float av = att[i];
        const int s0 = row_start[i*(NN+1) + row];
        const int s1 = row_start[i*(NN+1) + row + 1];
        const int* cp = colS + (size_t)i*NE;
        const float* vp = valS + (size_t)i*NE;
        for (int slot = s0; slot < s1; ++slot){
            int c = cp[slot];
            float v = vp[slot] * av;
            ushort4 u = *(const ushort4*)(feat + (size_t)c*DH + lane*4);
            a0 += v*bf2f(u.x); a1 += v*bf2f(u.y); a2 += v*bf2f(u.z); a3 += v*bf2f(u.w);
        }
    }
    // LeakyReLU(0.2)
    a0 = a0 > 0.f ? a0 : 0.2f*a0;
    a1 = a1 > 0.f ? a1 : 0.2f*a1;
    a2 = a2 > 0.f ? a2 : 0.2f*a2;
    a3 = a3 > 0.f ? a3 : 0.2f*a3;
    ushort4 o; o.x = f2bf(a0); o.y = f2bf(a1); o.z = f2bf(a2); o.w = f2bf(a3);
    *(ushort4*)(&out[(size_t)row*DH + lane*4]) = o;
}

// ---------------- SPMM layer2 (gather by src, fused L2 normalize) ----------------
__global__ __launch_bounds__(256) void k_spmm2(const unsigned short* __restrict__ feat,
                                               const int* __restrict__ row_start,
                                               const int* __restrict__ colS,
                                               const float* __restrict__ valS,
                                               const float* __restrict__ att,
                                               float* __restrict__ out){
    int row = __builtin_amdgcn_readfirstlane(blockIdx.x*4 + (threadIdx.x >> 6));
    int lane = threadIdx.x & 63;
    if (row >= NN) return;
    float a0=0.f, a1=0.f, a2=0.f, a3=0.f;
    #pragma unroll
    for (int i = 0; i < NRELS; ++i){
        const int a = NRELS + i;
        const float av = att[a];
        const int s0 = row_start[a*(NN+1) + row];
        const int s1 = row_start[a*(NN+1) + row + 1];
        const int* cp = colS + (size_t)a*NE;
        const float* vp = valS + (size_t)a*NE;
        for (int slot = s0; slot < s1; ++slot){
            int c = cp[slot];
            float v = vp[slot] * av;
            ushort4 u = *(const ushort4*)(feat + (size_t)c*DH + lane*4);
            a0 += v*bf2f(u.x); a1 += v*bf2f(u.y); a2 += v*bf2f(u.z); a3 += v*bf2f(u.w);
        }
    }
    float ss = a0*a0 + a1*a1 + a2*a2 + a3*a3;
    #pragma unroll
    for (int off = 32; off > 0; off >>= 1) ss += __shfl_xor(ss, off);
    float scale = 1.0f / fmaxf(sqrtf(ss), 1e-12f);
    float4 o; o.x = a0*scale; o.y = a1*scale; o.z = a2*scale; o.w = a3*scale;
    *(float4*)(&out[(size_t)row*DH + lane*4]) = o;
}

extern "C" void kernel_launch(void* const* d_in, const int* in_sizes, int n_in,
                              void* d_out, int out_size, void* d_ws, size_t ws_size,
                              hipStream_t stream){
    const float* x      = (const float*)d_in[0];
    const float* w1     = (const float*)d_in[1];
    const float* b1     = (const float*)d_in[2];
    const float* w2     = (const float*)d_in[3];
    const float* b2     = (const float*)d_in[4];
    const float* a_att  = (const float*)d_in[5];
    const float* r_att  = (const float*)d_in[6];
    const int*   src    = (const int*)d_in[7];
    const int*   dst    = (const int*)d_in[8];
    const float* vals_a = (const float*)d_in[9];
    const float* vals_r = (const float*)d_in[10];
    float* out = (float*)d_out;

    char* ws = (char*)d_ws;
    size_t off = 0;
    auto take = [&](size_t bytes)->char*{
        char* p = ws + off;
        off = (off + bytes + 255) & ~(size_t)255;
        return p;
    };
    float*          att       = (float*)take(6*sizeof(float));
    unsigned short* sbuf      = (unsigned short*)take((size_t)NN*DH*2); // s, later s2
    unsigned short* hbuf      = (unsigned short*)take((size_t)NN*DH*2); // h
    int*            counts    = (int*)take((size_t)6*NN*4);
    int*            cursor    = (int*)take((size_t)6*NN*4);
    int*            row_start = (int*)take((size_t)6*(NN+1)*4);
    int*            partials  = (int*)take((size_t)6*NCHUNK*4);
    int*            colS      = (int*)take((size_t)6*NE*4);
    float*          valS      = (float*)take((size_t)6*NE*4);
    (void)ws_size; (void)in_sizes; (void)n_in; (void)out_size;

    hipMemsetAsync(counts, 0, (size_t)6*NN*4, stream);
    hipMemsetAsync(cursor, 0, (size_t)6*NN*4, stream);

    k_att<<<1, 64, 0, stream>>>(a_att, r_att, att);

    dim3 egrid((NE + 255)/256, NRELS);
    k_hist<<<egrid, 256, 0, stream>>>(src, dst, counts);
    k_scanA<<<dim3(NCHUNK, 6), 256, 0, stream>>>(counts, partials);
    k_scanB<<<1, 256, 0, stream>>>(partials);
    k_scanC<<<dim3(NCHUNK, 6), 256, 0, stream>>>(counts, partials, row_start);
    k_scatter<<<egrid, 256, 0, stream>>>(src, dst, vals_a, vals_r, row_start, cursor, colS, valS);

    // layer 1: s = x@w1+b1 ; h = leaky(sum_i att[i]*spmm_i(s))
    k_gemm<DIN, 50, false><<<(NN + 31)/32, 256, 0, stream>>>(x, w1, b1, sbuf, NN);
    k_spmm1<<<(NN + 3)/4, 256, 0, stream>>>(sbuf, row_start, colS, valS, att, hbuf);

    // layer 2: s2 = h@w2+b2 (reuse sbuf) ; out = normalize(sum_i att2[i]*spmm_i(s2))
    k_gemm<DH, 64, true><<<(NN + 31)/32, 256, 0, stream>>>(hbuf, w2, b2, sbuf, NN);
    k_spmm2<<<(NN + 3)/4, 256, 0, stream>>>(sbuf, row_start, colS, valS, att, out);
}